// Round 1
// baseline (5618.870 us; speedup 1.0000x reference)
//
#include <hip/hip_runtime.h>
#include <math.h>

#define N_NODES 50000
#define N_EDGES 500000
#define D_IN 512
#define D_H  512
#define D_OUT 256

// ---------------- degree / norm ----------------

__global__ __launch_bounds__(256) void k_deg_init(int* __restrict__ deg) {
    int i = blockIdx.x * 256 + threadIdx.x;
    if (i < N_NODES) deg[i] = 1;  // self-loop
}

__global__ __launch_bounds__(256) void k_deg_hist(const int* __restrict__ dst,
                                                  int* __restrict__ deg) {
    int i = blockIdx.x * 256 + threadIdx.x;
    if (i < N_EDGES) atomicAdd(&deg[dst[i]], 1);
}

__global__ __launch_bounds__(256) void k_dinv(const int* __restrict__ deg,
                                              float* __restrict__ dinv) {
    int i = blockIdx.x * 256 + threadIdx.x;
    if (i < N_NODES) dinv[i] = rsqrtf((float)deg[i]);
}

// ---------------- fp32 GEMM: C[M,N] = A[M,K] @ B[K,N] ----------------
// 128x128 tile, 256 threads, 8x8 microtile, K-step 8, single-buffered LDS.

#define TM 128
#define TN 128
#define TK 8

__global__ __launch_bounds__(256) void k_sgemm(const float* __restrict__ A,
                                               const float* __restrict__ B,
                                               float* __restrict__ C,
                                               int M, int N, int K) {
    __shared__ float As[TK][TM + 4];  // [k][m], padded
    __shared__ float Bs[TK][TN + 4];  // [k][n], padded

    const int tid = threadIdx.x;
    const int bm = blockIdx.x * TM;
    const int bn = blockIdx.y * TN;
    const int tx = tid & 15;   // col group
    const int ty = tid >> 4;   // row group

    float acc[8][8];
#pragma unroll
    for (int i = 0; i < 8; ++i)
#pragma unroll
        for (int j = 0; j < 8; ++j) acc[i][j] = 0.f;

    // A-tile load mapping: 128 rows x 8 k, float4 along k; 2 threads per row
    const int arow = tid >> 1;          // 0..127
    const int acol = (tid & 1) << 2;    // 0 or 4
    // B-tile load mapping: 8 rows x 128 cols, float4 along n
    const int brow = tid >> 5;          // 0..7
    const int bcol = (tid & 31) << 2;   // 0..124

    const int gm = bm + arow;
    const bool aval = (gm < M);
    const float* aptr = A + (size_t)gm * K + acol;
    const float* bptr = B + (size_t)brow * N + bn + bcol;

    for (int kt = 0; kt < K; kt += TK) {
        float4 av = make_float4(0.f, 0.f, 0.f, 0.f);
        if (aval) av = *(const float4*)(aptr + kt);
        const float4 bv = *(const float4*)(bptr + (size_t)kt * N);

        __syncthreads();  // previous compute done reading LDS
        As[acol + 0][arow] = av.x;
        As[acol + 1][arow] = av.y;
        As[acol + 2][arow] = av.z;
        As[acol + 3][arow] = av.w;
        *(float4*)&Bs[brow][bcol] = bv;
        __syncthreads();

#pragma unroll
        for (int kk = 0; kk < TK; ++kk) {
            float a[8], b[8];
            *(float4*)&a[0] = *(const float4*)&As[kk][ty * 8];
            *(float4*)&a[4] = *(const float4*)&As[kk][ty * 8 + 4];
            *(float4*)&b[0] = *(const float4*)&Bs[kk][tx * 8];
            *(float4*)&b[4] = *(const float4*)&Bs[kk][tx * 8 + 4];
#pragma unroll
            for (int i = 0; i < 8; ++i)
#pragma unroll
                for (int j = 0; j < 8; ++j)
                    acc[i][j] = fmaf(a[i], b[j], acc[i][j]);
        }
    }

#pragma unroll
    for (int i = 0; i < 8; ++i) {
        const int row = bm + ty * 8 + i;
        if (row < M) {
            float* crow = C + (size_t)row * N + bn + tx * 8;
            *(float4*)crow = make_float4(acc[i][0], acc[i][1], acc[i][2], acc[i][3]);
            *(float4*)(crow + 4) = make_float4(acc[i][4], acc[i][5], acc[i][6], acc[i][7]);
        }
    }
}

// ---------------- aggregation ----------------

// out[n,:] = H[n,:] * dinv[n]^2   (self-loop term; also initializes out)
__global__ __launch_bounds__(256) void k_self_init(const float* __restrict__ H,
                                                   const float* __restrict__ dinv,
                                                   float* __restrict__ out, int ncols) {
    long long idx = (long long)blockIdx.x * 256 + threadIdx.x;  // float4 units
    const long long total = (long long)N_NODES * ncols / 4;
    if (idx >= total) return;
    const int row = (int)(idx / (ncols >> 2));
    float w = dinv[row];
    w *= w;
    float4 v = ((const float4*)H)[idx];
    v.x *= w; v.y *= w; v.z *= w; v.w *= w;
    ((float4*)out)[idx] = v;
}

// one wave per edge: out[dst,:] += H[src,:] * dinv[src]*dinv[dst]
__global__ __launch_bounds__(256) void k_scatter(const float* __restrict__ H,
                                                 float* __restrict__ out,
                                                 const int* __restrict__ src,
                                                 const int* __restrict__ dst,
                                                 const float* __restrict__ dinv,
                                                 int ncols) {
    const int wid = threadIdx.x >> 6;
    const int lane = threadIdx.x & 63;
    const int e = blockIdx.x * 4 + wid;
    if (e >= N_EDGES) return;
    const int s = src[e];
    const int d = dst[e];
    const float w = dinv[s] * dinv[d];
    const float4* hrow = (const float4*)(H + (size_t)s * ncols);
    float* orow = out + (size_t)d * ncols;
    const int n4 = ncols >> 2;
    for (int i = lane; i < n4; i += 64) {
        float4 v = hrow[i];
        atomicAdd(&orow[i * 4 + 0], v.x * w);
        atomicAdd(&orow[i * 4 + 1], v.y * w);
        atomicAdd(&orow[i * 4 + 2], v.z * w);
        atomicAdd(&orow[i * 4 + 3], v.w * w);
    }
}

// h = elu(h + bias), in place
__global__ __launch_bounds__(256) void k_bias_elu(float* __restrict__ h,
                                                  const float* __restrict__ bias,
                                                  int ncols) {
    long long idx = (long long)blockIdx.x * 256 + threadIdx.x;  // float4 units
    const long long total = (long long)N_NODES * ncols / 4;
    if (idx >= total) return;
    const int c4 = (int)(idx % (ncols >> 2)) * 4;
    float4 v = ((float4*)h)[idx];
    const float4 b = *(const float4*)(bias + c4);
    v.x += b.x; v.y += b.y; v.z += b.z; v.w += b.w;
    v.x = v.x > 0.f ? v.x : expf(v.x) - 1.f;
    v.y = v.y > 0.f ? v.y : expf(v.y) - 1.f;
    v.z = v.z > 0.f ? v.z : expf(v.z) - 1.f;
    v.w = v.w > 0.f ? v.w : expf(v.w) - 1.f;
    ((float4*)h)[idx] = v;
}

// ---------------- launch ----------------

extern "C" void kernel_launch(void* const* d_in, const int* in_sizes, int n_in,
                              void* d_out, int out_size, void* d_ws, size_t ws_size,
                              hipStream_t stream) {
    const float* x  = (const float*)d_in[0];
    const int* ei   = (const int*)d_in[1];
    const int* src  = ei;            // edge_index[0]
    const int* dst  = ei + N_EDGES;  // edge_index[1]
    const float* W1 = (const float*)d_in[2];
    const float* b1 = (const float*)d_in[3];
    const float* W2 = (const float*)d_in[4];
    const float* b2 = (const float*)d_in[5];
    float* out = (float*)d_out;

    char* ws = (char*)d_ws;
    size_t off = 0;
    auto alloc = [&](size_t bytes) -> void* {
        void* p = ws + off;
        off = (off + bytes + 255) & ~(size_t)255;
        return p;
    };
    int*   deg  = (int*)alloc((size_t)N_NODES * 4);
    float* dinv = (float*)alloc((size_t)N_NODES * 4);
    float* H1   = (float*)alloc((size_t)N_NODES * D_H * 4);   // 102.4 MB
    float* out1 = (float*)alloc((size_t)N_NODES * D_H * 4);   // 102.4 MB
    float* H2   = H1;  // H1 dead once GEMM2 starts (reads out1, writes H2)

    // degrees + norm
    k_deg_init<<<(N_NODES + 255) / 256, 256, 0, stream>>>(deg);
    k_deg_hist<<<(N_EDGES + 255) / 256, 256, 0, stream>>>(dst, deg);
    k_dinv<<<(N_NODES + 255) / 256, 256, 0, stream>>>(deg, dinv);

    // ----- layer 1 -----
    dim3 g1((N_NODES + TM - 1) / TM, D_H / TN);
    k_sgemm<<<g1, 256, 0, stream>>>(x, W1, H1, N_NODES, D_H, D_IN);

    const long long tot1 = (long long)N_NODES * D_H / 4;
    k_self_init<<<(int)((tot1 + 255) / 256), 256, 0, stream>>>(H1, dinv, out1, D_H);
    k_scatter<<<(N_EDGES + 3) / 4, 256, 0, stream>>>(H1, out1, src, dst, dinv, D_H);
    k_bias_elu<<<(int)((tot1 + 255) / 256), 256, 0, stream>>>(out1, b1, D_H);

    // ----- layer 2 -----
    dim3 g2((N_NODES + TM - 1) / TM, D_OUT / TN);
    k_sgemm<<<g2, 256, 0, stream>>>(out1, W2, H2, N_NODES, D_OUT, D_H);

    const long long tot2 = (long long)N_NODES * D_OUT / 4;
    k_self_init<<<(int)((tot2 + 255) / 256), 256, 0, stream>>>(H2, dinv, out, D_OUT);
    k_scatter<<<(N_EDGES + 3) / 4, 256, 0, stream>>>(H2, out, src, dst, dinv, D_OUT);
    k_bias_elu<<<(int)((tot2 + 255) / 256), 256, 0, stream>>>(out, b2, D_OUT);
}

// Round 2
// 1040.151 us; speedup vs baseline: 5.4020x; 5.4020x over previous
//
#include <hip/hip_runtime.h>
#include <math.h>

#define N_NODES 50000
#define N_EDGES 500000
#define D_IN 512
#define D_H  512
#define D_OUT 256

// ---------------- degree / CSR build ----------------

__global__ __launch_bounds__(256) void k_zero(int* __restrict__ p, int n) {
    int i = blockIdx.x * 256 + threadIdx.x;
    if (i < n) p[i] = 0;
}

__global__ __launch_bounds__(256) void k_indeg(const int* __restrict__ dst,
                                               int* __restrict__ indeg) {
    int i = blockIdx.x * 256 + threadIdx.x;
    if (i < N_EDGES) atomicAdd(&indeg[dst[i]], 1);
}

__global__ __launch_bounds__(256) void k_dinv(const int* __restrict__ indeg,
                                              float* __restrict__ dinv) {
    int i = blockIdx.x * 256 + threadIdx.x;
    if (i < N_NODES) dinv[i] = rsqrtf((float)(1 + indeg[i]));  // +1 self-loop
}

// single-block exclusive scan of indeg -> row_start[0..N], cursor = row_start copy
__global__ __launch_bounds__(256) void k_scan(const int* __restrict__ indeg,
                                              int* __restrict__ row_start,
                                              int* __restrict__ cursor) {
    __shared__ int buf[256];
    __shared__ int carry_s;
    const int tid = threadIdx.x;
    if (tid == 0) carry_s = 0;
    __syncthreads();
    for (int base = 0; base < N_NODES; base += 256) {
        const int i = base + tid;
        const int v = (i < N_NODES) ? indeg[i] : 0;
        buf[tid] = v;
        __syncthreads();
#pragma unroll
        for (int ofs = 1; ofs < 256; ofs <<= 1) {
            int t = (tid >= ofs) ? buf[tid - ofs] : 0;
            __syncthreads();
            buf[tid] += t;
            __syncthreads();
        }
        const int excl = carry_s + buf[tid] - v;
        if (i < N_NODES) { row_start[i] = excl; cursor[i] = excl; }
        __syncthreads();
        if (tid == 255) carry_s += buf[255];
        __syncthreads();
    }
    if (tid == 0) row_start[N_NODES] = carry_s;  // == N_EDGES
}

__global__ __launch_bounds__(256) void k_bucket(const int* __restrict__ src,
                                                const int* __restrict__ dst,
                                                int* __restrict__ cursor,
                                                int* __restrict__ csr_src) {
    int e = blockIdx.x * 256 + threadIdx.x;
    if (e >= N_EDGES) return;
    int pos = atomicAdd(&cursor[dst[e]], 1);
    csr_src[pos] = src[e];
}

// ---------------- fp32 GEMM: C[M,N] = A[M,K] @ B[K,N] ----------------

#define TM 128
#define TN 128
#define TK 8

__global__ __launch_bounds__(256) void k_sgemm(const float* __restrict__ A,
                                               const float* __restrict__ B,
                                               float* __restrict__ C,
                                               int M, int N, int K) {
    __shared__ float As[TK][TM + 4];
    __shared__ float Bs[TK][TN + 4];

    const int tid = threadIdx.x;
    const int bm = blockIdx.x * TM;
    const int bn = blockIdx.y * TN;
    const int tx = tid & 15;
    const int ty = tid >> 4;

    float acc[8][8];
#pragma unroll
    for (int i = 0; i < 8; ++i)
#pragma unroll
        for (int j = 0; j < 8; ++j) acc[i][j] = 0.f;

    const int arow = tid >> 1;
    const int acol = (tid & 1) << 2;
    const int brow = tid >> 5;
    const int bcol = (tid & 31) << 2;

    const int gm = bm + arow;
    const bool aval = (gm < M);
    const float* aptr = A + (size_t)gm * K + acol;
    const float* bptr = B + (size_t)brow * N + bn + bcol;

    for (int kt = 0; kt < K; kt += TK) {
        float4 av = make_float4(0.f, 0.f, 0.f, 0.f);
        if (aval) av = *(const float4*)(aptr + kt);
        const float4 bv = *(const float4*)(bptr + (size_t)kt * N);

        __syncthreads();
        As[acol + 0][arow] = av.x;
        As[acol + 1][arow] = av.y;
        As[acol + 2][arow] = av.z;
        As[acol + 3][arow] = av.w;
        *(float4*)&Bs[brow][bcol] = bv;
        __syncthreads();

#pragma unroll
        for (int kk = 0; kk < TK; ++kk) {
            float a[8], b[8];
            *(float4*)&a[0] = *(const float4*)&As[kk][ty * 8];
            *(float4*)&a[4] = *(const float4*)&As[kk][ty * 8 + 4];
            *(float4*)&b[0] = *(const float4*)&Bs[kk][tx * 8];
            *(float4*)&b[4] = *(const float4*)&Bs[kk][tx * 8 + 4];
#pragma unroll
            for (int i = 0; i < 8; ++i)
#pragma unroll
                for (int j = 0; j < 8; ++j)
                    acc[i][j] = fmaf(a[i], b[j], acc[i][j]);
        }
    }

#pragma unroll
    for (int i = 0; i < 8; ++i) {
        const int row = bm + ty * 8 + i;
        if (row < M) {
            float* crow = C + (size_t)row * N + bn + tx * 8;
            *(float4*)crow = make_float4(acc[i][0], acc[i][1], acc[i][2], acc[i][3]);
            *(float4*)(crow + 4) = make_float4(acc[i][4], acc[i][5], acc[i][6], acc[i][7]);
        }
    }
}

// ---------------- fused aggregate: self + gather + bias + ELU ----------------
// one wave per node: out[n,:] = elu( dinv[n]^2*H[n,:] + sum_e dinv[s]*dinv[n]*H[s,:] + bias )

template <int NC4>  // ncols/4: 128 (D=512) or 64 (D=256)
__global__ __launch_bounds__(256) void k_aggregate(const float* __restrict__ H,
                                                   const float* __restrict__ bias,
                                                   float* __restrict__ out,
                                                   const int* __restrict__ row_start,
                                                   const int* __restrict__ csr_src,
                                                   const float* __restrict__ dinv) {
    const int wid = threadIdx.x >> 6;
    const int lane = threadIdx.x & 63;
    const int n = blockIdx.x * 4 + wid;
    if (n >= N_NODES) return;

    const float di = dinv[n];
    const int ncols = NC4 * 4;
    constexpr int R = (NC4 + 63) / 64;  // 2 for 512, 1 for 256

    float4 acc[R];
    {
        const float w = di * di;
        const float4* hrow = (const float4*)(H + (size_t)n * ncols);
#pragma unroll
        for (int r = 0; r < R; ++r) {
            const int c = lane + r * 64;
            float4 v = hrow[c];
            acc[r] = make_float4(v.x * w, v.y * w, v.z * w, v.w * w);
        }
    }

    const int e0 = row_start[n];
    const int e1 = row_start[n + 1];
    for (int j = e0; j < e1; ++j) {
        const int s = csr_src[j];
        const float w = dinv[s] * di;
        const float4* hs = (const float4*)(H + (size_t)s * ncols);
#pragma unroll
        for (int r = 0; r < R; ++r) {
            const int c = lane + r * 64;
            float4 v = hs[c];
            acc[r].x = fmaf(v.x, w, acc[r].x);
            acc[r].y = fmaf(v.y, w, acc[r].y);
            acc[r].z = fmaf(v.z, w, acc[r].z);
            acc[r].w = fmaf(v.w, w, acc[r].w);
        }
    }

    float* orow = out + (size_t)n * ncols;
#pragma unroll
    for (int r = 0; r < R; ++r) {
        const int c = lane + r * 64;
        const float4 b = ((const float4*)bias)[c];
        float4 v = acc[r];
        v.x += b.x; v.y += b.y; v.z += b.z; v.w += b.w;
        v.x = v.x > 0.f ? v.x : expf(v.x) - 1.f;
        v.y = v.y > 0.f ? v.y : expf(v.y) - 1.f;
        v.z = v.z > 0.f ? v.z : expf(v.z) - 1.f;
        v.w = v.w > 0.f ? v.w : expf(v.w) - 1.f;
        ((float4*)orow)[c] = v;
    }
}

// ---------------- launch ----------------

extern "C" void kernel_launch(void* const* d_in, const int* in_sizes, int n_in,
                              void* d_out, int out_size, void* d_ws, size_t ws_size,
                              hipStream_t stream) {
    const float* x  = (const float*)d_in[0];
    const int* ei   = (const int*)d_in[1];
    const int* src  = ei;
    const int* dst  = ei + N_EDGES;
    const float* W1 = (const float*)d_in[2];
    const float* b1 = (const float*)d_in[3];
    const float* W2 = (const float*)d_in[4];
    const float* b2 = (const float*)d_in[5];
    float* out = (float*)d_out;

    char* ws = (char*)d_ws;
    size_t off = 0;
    auto alloc = [&](size_t bytes) -> void* {
        void* p = ws + off;
        off = (off + bytes + 255) & ~(size_t)255;
        return p;
    };
    int*   indeg     = (int*)alloc((size_t)N_NODES * 4);
    int*   row_start = (int*)alloc((size_t)(N_NODES + 1) * 4);
    int*   cursor    = (int*)alloc((size_t)N_NODES * 4);
    int*   csr_src   = (int*)alloc((size_t)N_EDGES * 4);
    float* dinv      = (float*)alloc((size_t)N_NODES * 4);
    float* H1        = (float*)alloc((size_t)N_NODES * D_H * 4);
    float* out1      = (float*)alloc((size_t)N_NODES * D_H * 4);
    float* H2        = H1;  // H1 dead once GEMM2 runs

    // CSR build (per call; deterministic up to within-bucket order)
    k_zero<<<(N_NODES + 255) / 256, 256, 0, stream>>>(indeg, N_NODES);
    k_indeg<<<(N_EDGES + 255) / 256, 256, 0, stream>>>(dst, indeg);
    k_dinv<<<(N_NODES + 255) / 256, 256, 0, stream>>>(indeg, dinv);
    k_scan<<<1, 256, 0, stream>>>(indeg, row_start, cursor);
    k_bucket<<<(N_EDGES + 255) / 256, 256, 0, stream>>>(src, dst, cursor, csr_src);

    // ----- layer 1 -----
    dim3 g1((N_NODES + TM - 1) / TM, D_H / TN);
    k_sgemm<<<g1, 256, 0, stream>>>(x, W1, H1, N_NODES, D_H, D_IN);
    k_aggregate<128><<<(N_NODES + 3) / 4, 256, 0, stream>>>(H1, b1, out1, row_start, csr_src, dinv);

    // ----- layer 2 -----
    dim3 g2((N_NODES + TM - 1) / TM, D_OUT / TN);
    k_sgemm<<<g2, 256, 0, stream>>>(out1, W2, H2, N_NODES, D_OUT, D_H);
    k_aggregate<64><<<(N_NODES + 3) / 4, 256, 0, stream>>>(H2, b2, out, row_start, csr_src, dinv);
}

// Round 3
// 390.063 us; speedup vs baseline: 14.4050x; 2.6666x over previous
//
#include <hip/hip_runtime.h>
#include <math.h>

#define N_NODES 50000
#define N_EDGES 500000
#define D_IN 512
#define D_H  512
#define D_OUT 256

typedef __attribute__((ext_vector_type(8))) short bf16x8;
typedef __attribute__((ext_vector_type(8))) unsigned short ushort8;
typedef __attribute__((ext_vector_type(4))) float f32x4;

__device__ __forceinline__ float b2f(unsigned short u) {
    union { unsigned int i; float f; } v; v.i = ((unsigned int)u) << 16; return v.f;
}
__device__ __forceinline__ unsigned short f2b(float f) {
    unsigned int x = __float_as_uint(f);
    unsigned int r = (x + 0x7fffu + ((x >> 16) & 1u)) >> 16;  // RNE
    return (unsigned short)r;
}

// ---------------- conversions ----------------

__global__ __launch_bounds__(256) void k_cvt(const float* __restrict__ in,
                                             unsigned short* __restrict__ out,
                                             long long n4) {
    long long i = (long long)blockIdx.x * 256 + threadIdx.x;
    if (i >= n4) return;
    float4 v = ((const float4*)in)[i];
    ushort4 o;
    o.x = f2b(v.x); o.y = f2b(v.y); o.z = f2b(v.z); o.w = f2b(v.w);
    ((ushort4*)out)[i] = o;
}

// W [K][N] fp32 -> Wt [N][K] bf16
__global__ void k_wt(const float* __restrict__ W, unsigned short* __restrict__ Wt,
                     int K, int N) {
    __shared__ float t[32][33];
    const int bk = blockIdx.x * 32, bn = blockIdx.y * 32;
    const int tx = threadIdx.x, ty = threadIdx.y;  // (32,8)
    for (int i = ty; i < 32; i += 8) t[i][tx] = W[(size_t)(bk + i) * N + bn + tx];
    __syncthreads();
    for (int i = ty; i < 32; i += 8)
        Wt[(size_t)(bn + i) * K + bk + tx] = f2b(t[tx][i]);
}

// ---------------- degree / CSR build ----------------

__global__ __launch_bounds__(256) void k_zero(int* __restrict__ p, int n) {
    int i = blockIdx.x * 256 + threadIdx.x;
    if (i < n) p[i] = 0;
}

__global__ __launch_bounds__(256) void k_indeg(const int* __restrict__ dst,
                                               int* __restrict__ indeg) {
    int i = blockIdx.x * 256 + threadIdx.x;
    if (i < N_EDGES) atomicAdd(&indeg[dst[i]], 1);
}

__global__ __launch_bounds__(256) void k_dinv(const int* __restrict__ indeg,
                                              float* __restrict__ dinv) {
    int i = blockIdx.x * 256 + threadIdx.x;
    if (i < N_NODES) dinv[i] = rsqrtf((float)(1 + indeg[i]));
}

// single-block scan, 1024 threads, shfl-based
__global__ __launch_bounds__(1024) void k_scan(const int* __restrict__ indeg,
                                               int* __restrict__ row_start,
                                               int* __restrict__ cursor) {
    __shared__ int wsum[16];
    __shared__ int carry_s;
    const int tid = threadIdx.x, lane = tid & 63, w = tid >> 6;
    if (tid == 0) carry_s = 0;
    __syncthreads();
    for (int base = 0; base < N_NODES; base += 1024) {
        const int i = base + tid;
        const int v = (i < N_NODES) ? indeg[i] : 0;
        int s = v;
#pragma unroll
        for (int o = 1; o < 64; o <<= 1) {
            int t = __shfl_up(s, o, 64);
            if (lane >= o) s += t;
        }
        if (lane == 63) wsum[w] = s;
        __syncthreads();
        if (w == 0 && lane < 16) {
            int t = wsum[lane];
#pragma unroll
            for (int o = 1; o < 16; o <<= 1) {
                int u = __shfl_up(t, o, 64);
                if (lane >= o) t += u;
            }
            wsum[lane] = t;  // inclusive scan of wave sums
        }
        __syncthreads();
        const int woff = (w == 0) ? 0 : wsum[w - 1];
        const int incl = carry_s + woff + s;
        if (i < N_NODES) { row_start[i] = incl - v; cursor[i] = incl - v; }
        __syncthreads();
        if (tid == 0) carry_s += wsum[15];
        __syncthreads();
    }
    if (tid == 0) row_start[N_NODES] = carry_s;
}

__global__ __launch_bounds__(256) void k_bucket(const int* __restrict__ src,
                                                const int* __restrict__ dst,
                                                int* __restrict__ cursor,
                                                int* __restrict__ csr_src) {
    int e = blockIdx.x * 256 + threadIdx.x;
    if (e >= N_EDGES) return;
    int pos = atomicAdd(&cursor[dst[e]], 1);
    csr_src[pos] = src[e];
}

// ---------------- bf16 MFMA GEMM ----------------
// C[M,N] = A[M,K] @ Bt[N,K]^T, all bf16, fp32 accum. 128x128 tile, BK=32,
// 256 threads = 4 waves in 2x2, each wave 64x64 (4x4 frags of 16x16x32).

__device__ __forceinline__ void gload16(const void* g, void* l) {
    __builtin_amdgcn_global_load_lds(
        (const __attribute__((address_space(1))) unsigned int*)g,
        (__attribute__((address_space(3))) unsigned int*)l, 16, 0, 0);
}

__global__ __launch_bounds__(256) void k_gemm_bf16(const unsigned short* __restrict__ A,
                                                   const unsigned short* __restrict__ Bt,
                                                   unsigned short* __restrict__ C,
                                                   int M, int N, int K) {
    __shared__ __align__(16) short As[128 * 32];
    __shared__ __align__(16) short Bs[128 * 32];

    const int tid = threadIdx.x;
    const int w = tid >> 6;        // wave 0..3
    const int lane = tid & 63;
    const int wr = w >> 1, wc = w & 1;
    const int brow = blockIdx.x * 128;
    const int bcol = blockIdx.y * 128;

    const int lhi = lane >> 4;     // 0..3
    const int llo = lane & 15;

    f32x4 acc[4][4];
#pragma unroll
    for (int i = 0; i < 4; ++i)
#pragma unroll
        for (int j = 0; j < 4; ++j) acc[i][j] = (f32x4){0.f, 0.f, 0.f, 0.f};

    // staging geometry: per wave, 2 issues of 16 rows for A and for B
    const int srow = lane >> 2;        // 0..15 within 16-row group
    const int schunk = (lane & 3) * 8; // bf16 elems within 32-k row

    for (int kt = 0; kt < K; kt += 32) {
        __syncthreads();
#pragma unroll
        for (int i = 0; i < 2; ++i) {
            const int rbase = w * 32 + i * 16;
            int gr = brow + rbase + srow;
            gr = gr < M ? gr : M - 1;
            gload16(A + (size_t)gr * K + kt + schunk, &As[rbase * 32]);
            const int gc = bcol + rbase + srow;
            gload16(Bt + (size_t)gc * K + kt + schunk, &Bs[rbase * 32]);
        }
        __syncthreads();

        bf16x8 af[4], bf[4];
#pragma unroll
        for (int mi = 0; mi < 4; ++mi)
            af[mi] = *(const bf16x8*)&As[(wr * 64 + mi * 16 + llo) * 32 + lhi * 8];
#pragma unroll
        for (int ni = 0; ni < 4; ++ni)
            bf[ni] = *(const bf16x8*)&Bs[(wc * 64 + ni * 16 + llo) * 32 + lhi * 8];
#pragma unroll
        for (int mi = 0; mi < 4; ++mi)
#pragma unroll
            for (int ni = 0; ni < 4; ++ni)
                acc[mi][ni] = __builtin_amdgcn_mfma_f32_16x16x32_bf16(
                    af[mi], bf[ni], acc[mi][ni], 0, 0, 0);
    }

    // store: D row = lhi*4 + r, col = llo (within 16x16 frag)
#pragma unroll
    for (int mi = 0; mi < 4; ++mi) {
        const int row0 = brow + wr * 64 + mi * 16 + lhi * 4;
#pragma unroll
        for (int ni = 0; ni < 4; ++ni) {
            const int col = bcol + wc * 64 + ni * 16 + llo;
            const f32x4 v = acc[mi][ni];
#pragma unroll
            for (int r = 0; r < 4; ++r) {
                const int row = row0 + r;
                if (row < M) C[(size_t)row * N + col] = f2b(v[r]);
            }
        }
    }
}

// ---------------- fused aggregate: self + gather + bias + ELU ----------------
// H is bf16 [N_NODES][D]; out is bf16 (layer1) or fp32 (layer2).

template <int D, bool BF16_OUT>
__global__ __launch_bounds__(256) void k_aggregate(const unsigned short* __restrict__ H,
                                                   const float* __restrict__ bias,
                                                   void* __restrict__ outv,
                                                   const int* __restrict__ row_start,
                                                   const int* __restrict__ csr_src,
                                                   const float* __restrict__ dinv) {
    const int wid = threadIdx.x >> 6;
    const int lane = threadIdx.x & 63;
    int n, c0;
    if (D == 512) { n = blockIdx.x * 4 + wid; c0 = lane * 8; }
    else          { n = blockIdx.x * 8 + wid * 2 + (lane >> 5); c0 = (lane & 31) * 8; }
    if (n >= N_NODES) return;

    const float di = dinv[n];
    float acc[8];
    {
        const float ws = di * di;
        ushort8 v = *(const ushort8*)(H + (size_t)n * D + c0);
#pragma unroll
        for (int e = 0; e < 8; ++e) acc[e] = b2f(v[e]) * ws;
    }

    const int e0 = row_start[n];
    const int e1 = row_start[n + 1];
    for (int j = e0; j < e1; ++j) {
        const int s = csr_src[j];
        const float ws = dinv[s] * di;
        ushort8 v = *(const ushort8*)(H + (size_t)s * D + c0);
#pragma unroll
        for (int e = 0; e < 8; ++e) acc[e] = fmaf(b2f(v[e]), ws, acc[e]);
    }

#pragma unroll
    for (int e = 0; e < 8; ++e) {
        float t = acc[e] + bias[c0 + e];
        acc[e] = t > 0.f ? t : expf(t) - 1.f;
    }

    if (BF16_OUT) {
        ushort8 o;
#pragma unroll
        for (int e = 0; e < 8; ++e) o[e] = f2b(acc[e]);
        *(ushort8*)((unsigned short*)outv + (size_t)n * D + c0) = o;
    } else {
        float* orow = (float*)outv + (size_t)n * D + c0;
        *(float4*)orow = make_float4(acc[0], acc[1], acc[2], acc[3]);
        *(float4*)(orow + 4) = make_float4(acc[4], acc[5], acc[6], acc[7]);
    }
}

// ---------------- launch ----------------

extern "C" void kernel_launch(void* const* d_in, const int* in_sizes, int n_in,
                              void* d_out, int out_size, void* d_ws, size_t ws_size,
                              hipStream_t stream) {
    const float* x  = (const float*)d_in[0];
    const int* ei   = (const int*)d_in[1];
    const int* src  = ei;
    const int* dst  = ei + N_EDGES;
    const float* W1 = (const float*)d_in[2];
    const float* b1 = (const float*)d_in[3];
    const float* W2 = (const float*)d_in[4];
    const float* b2 = (const float*)d_in[5];
    float* out = (float*)d_out;

    char* ws = (char*)d_ws;
    size_t off = 0;
    auto alloc = [&](size_t bytes) -> void* {
        void* p = ws + off;
        off = (off + bytes + 255) & ~(size_t)255;
        return p;
    };
    int*   indeg     = (int*)alloc((size_t)N_NODES * 4);
    int*   row_start = (int*)alloc((size_t)(N_NODES + 1) * 4);
    int*   cursor    = (int*)alloc((size_t)N_NODES * 4);
    int*   csr_src   = (int*)alloc((size_t)N_EDGES * 4);
    float* dinv      = (float*)alloc((size_t)N_NODES * 4);
    unsigned short* xb   = (unsigned short*)alloc((size_t)N_NODES * D_IN * 2);  // 51.2 MB
    unsigned short* W1t  = (unsigned short*)alloc((size_t)D_H * D_IN * 2);
    unsigned short* W2t  = (unsigned short*)alloc((size_t)D_OUT * D_H * 2);
    unsigned short* H1   = (unsigned short*)alloc((size_t)N_NODES * D_H * 2);   // 51.2 MB
    unsigned short* out1 = (unsigned short*)alloc((size_t)N_NODES * D_H * 2);   // 51.2 MB
    unsigned short* H2   = (unsigned short*)alloc((size_t)N_NODES * D_OUT * 2); // 25.6 MB

    // CSR build + norms
    k_zero<<<(N_NODES + 255) / 256, 256, 0, stream>>>(indeg, N_NODES);
    k_indeg<<<(N_EDGES + 255) / 256, 256, 0, stream>>>(dst, indeg);
    k_dinv<<<(N_NODES + 255) / 256, 256, 0, stream>>>(indeg, dinv);
    k_scan<<<1, 1024, 0, stream>>>(indeg, row_start, cursor);
    k_bucket<<<(N_EDGES + 255) / 256, 256, 0, stream>>>(src, dst, cursor, csr_src);

    // input conversions
    const long long x4 = (long long)N_NODES * D_IN / 4;
    k_cvt<<<(int)((x4 + 255) / 256), 256, 0, stream>>>(x, xb, x4);
    {
        dim3 b(32, 8);
        dim3 g1(D_IN / 32, D_H / 32);
        k_wt<<<g1, b, 0, stream>>>(W1, W1t, D_IN, D_H);
        dim3 g2(D_H / 32, D_OUT / 32);
        k_wt<<<g2, b, 0, stream>>>(W2, W2t, D_H, D_OUT);
    }

    // ----- layer 1 -----
    dim3 gg1((N_NODES + 127) / 128, D_H / 128);
    k_gemm_bf16<<<gg1, 256, 0, stream>>>(xb, W1t, H1, N_NODES, D_H, D_IN);
    k_aggregate<512, true><<<(N_NODES + 3) / 4, 256, 0, stream>>>(H1, b1, out1, row_start, csr_src, dinv);

    // ----- layer 2 -----
    dim3 gg2((N_NODES + 127) / 128, D_OUT / 128);
    k_gemm_bf16<<<gg2, 256, 0, stream>>>(out1, W2t, H2, N_NODES, D_OUT, D_H);
    k_aggregate<256, false><<<(N_NODES + 7) / 8, 256, 0, stream>>>(H2, b2, out, row_start, csr_src, dinv);
}

// Round 4
// 314.525 us; speedup vs baseline: 17.8646x; 1.2402x over previous
//
#include <hip/hip_runtime.h>
#include <math.h>

#define N_NODES 50000
#define N_EDGES 500000
#define D_IN 512
#define D_H  512
#define D_OUT 256
#define NB 196  // ceil(N_NODES/256)

typedef __attribute__((ext_vector_type(8))) short bf16x8;
typedef __attribute__((ext_vector_type(8))) unsigned short ushort8;
typedef __attribute__((ext_vector_type(4))) float f32x4;

__device__ __forceinline__ float b2f(unsigned short u) {
    union { unsigned int i; float f; } v; v.i = ((unsigned int)u) << 16; return v.f;
}
__device__ __forceinline__ unsigned short f2b(float f) {
    unsigned int x = __float_as_uint(f);
    unsigned int r = (x + 0x7fffu + ((x >> 16) & 1u)) >> 16;  // RNE
    return (unsigned short)r;
}

// ---------------- weight transpose: W [K][N] fp32 -> Wt [N][K] bf16 ----------------

__global__ void k_wt(const float* __restrict__ W, unsigned short* __restrict__ Wt,
                     int K, int N) {
    __shared__ float t[32][33];
    const int bk = blockIdx.x * 32, bn = blockIdx.y * 32;
    const int tx = threadIdx.x, ty = threadIdx.y;  // (32,8)
    for (int i = ty; i < 32; i += 8) t[i][tx] = W[(size_t)(bk + i) * N + bn + tx];
    __syncthreads();
    for (int i = ty; i < 32; i += 8)
        Wt[(size_t)(bn + i) * K + bk + tx] = f2b(t[tx][i]);
}

// ---------------- degree / CSR build ----------------

__global__ __launch_bounds__(256) void k_zero(int* __restrict__ p, int n) {
    int i = blockIdx.x * 256 + threadIdx.x;
    if (i < n) p[i] = 0;
}

__global__ __launch_bounds__(256) void k_indeg(const int* __restrict__ dst,
                                               int* __restrict__ indeg) {
    int i = blockIdx.x * 256 + threadIdx.x;
    if (i < N_EDGES) atomicAdd(&indeg[dst[i]], 1);
}

// per-block sums of indeg
__global__ __launch_bounds__(256) void k_partials(const int* __restrict__ indeg,
                                                  int* __restrict__ bsum) {
    __shared__ int wsum[4];
    const int tid = threadIdx.x, lane = tid & 63, w = tid >> 6;
    const int i = blockIdx.x * 256 + tid;
    int v = (i < N_NODES) ? indeg[i] : 0;
#pragma unroll
    for (int o = 32; o > 0; o >>= 1) v += __shfl_down(v, o, 64);
    if (lane == 0) wsum[w] = v;
    __syncthreads();
    if (tid == 0) bsum[blockIdx.x] = wsum[0] + wsum[1] + wsum[2] + wsum[3];
}

// exclusive scan of NB block sums
__global__ __launch_bounds__(256) void k_scanb(const int* __restrict__ bsum,
                                               int* __restrict__ boff) {
    __shared__ int wsum[4];
    const int tid = threadIdx.x, lane = tid & 63, w = tid >> 6;
    const int v = (tid < NB) ? bsum[tid] : 0;
    int s = v;
#pragma unroll
    for (int o = 1; o < 64; o <<= 1) {
        int t = __shfl_up(s, o, 64);
        if (lane >= o) s += t;
    }
    if (lane == 63) wsum[w] = s;
    __syncthreads();
    int add = 0;
    for (int k = 0; k < w; ++k) add += wsum[k];
    if (tid < NB) boff[tid] = add + s - v;
}

// per-element exclusive scan + dinv
__global__ __launch_bounds__(256) void k_finalize(const int* __restrict__ indeg,
                                                  const int* __restrict__ boff,
                                                  int* __restrict__ row_start,
                                                  int* __restrict__ cursor,
                                                  float* __restrict__ dinv) {
    __shared__ int wsum[4];
    const int tid = threadIdx.x, lane = tid & 63, w = tid >> 6;
    const int i = blockIdx.x * 256 + tid;
    const int v = (i < N_NODES) ? indeg[i] : 0;
    int s = v;
#pragma unroll
    for (int o = 1; o < 64; o <<= 1) {
        int t = __shfl_up(s, o, 64);
        if (lane >= o) s += t;
    }
    if (lane == 63) wsum[w] = s;
    __syncthreads();
    int add = boff[blockIdx.x];
    for (int k = 0; k < w; ++k) add += wsum[k];
    if (i < N_NODES) {
        const int excl = add + s - v;
        row_start[i] = excl;
        cursor[i] = excl;
        dinv[i] = rsqrtf((float)(1 + v));
    }
    if (i == N_NODES) row_start[N_NODES] = N_EDGES;
}

__global__ __launch_bounds__(256) void k_bucket(const int* __restrict__ src,
                                                const int* __restrict__ dst,
                                                int* __restrict__ cursor,
                                                int* __restrict__ csr_src) {
    int e = blockIdx.x * 256 + threadIdx.x;
    if (e >= N_EDGES) return;
    int pos = atomicAdd(&cursor[dst[e]], 1);
    csr_src[pos] = src[e];
}

// ---------------- bf16 MFMA GEMM ----------------
// C[M,N] = A[M,K] @ Bt[N,K]^T, fp32 accum -> bf16 C. 128x128 tile, BK=32,
// 256 threads = 4 waves in 2x2, each wave 64x64 (4x4 frags of 16x16x32).

__device__ __forceinline__ void gload16(const void* g, void* l) {
    __builtin_amdgcn_global_load_lds(
        (const __attribute__((address_space(1))) unsigned int*)g,
        (__attribute__((address_space(3))) unsigned int*)l, 16, 0, 0);
}

// A is bf16 (layer 2)
__global__ __launch_bounds__(256) void k_gemm_bf16(const unsigned short* __restrict__ A,
                                                   const unsigned short* __restrict__ Bt,
                                                   unsigned short* __restrict__ C,
                                                   int M, int N, int K) {
    __shared__ __align__(16) short As[128 * 32];
    __shared__ __align__(16) short Bs[128 * 32];

    const int tid = threadIdx.x;
    const int w = tid >> 6;
    const int lane = tid & 63;
    const int wr = w >> 1, wc = w & 1;
    const int brow = blockIdx.x * 128;
    const int bcol = blockIdx.y * 128;
    const int lhi = lane >> 4;
    const int llo = lane & 15;

    f32x4 acc[4][4];
#pragma unroll
    for (int i = 0; i < 4; ++i)
#pragma unroll
        for (int j = 0; j < 4; ++j) acc[i][j] = (f32x4){0.f, 0.f, 0.f, 0.f};

    const int srow = lane >> 2;
    const int schunk = (lane & 3) * 8;

    for (int kt = 0; kt < K; kt += 32) {
        __syncthreads();
#pragma unroll
        for (int i = 0; i < 2; ++i) {
            const int rbase = w * 32 + i * 16;
            int gr = brow + rbase + srow;
            gr = gr < M ? gr : M - 1;
            gload16(A + (size_t)gr * K + kt + schunk, &As[rbase * 32]);
            const int gc = bcol + rbase + srow;
            gload16(Bt + (size_t)gc * K + kt + schunk, &Bs[rbase * 32]);
        }
        __syncthreads();

        bf16x8 af[4], bfr[4];
#pragma unroll
        for (int mi = 0; mi < 4; ++mi)
            af[mi] = *(const bf16x8*)&As[(wr * 64 + mi * 16 + llo) * 32 + lhi * 8];
#pragma unroll
        for (int ni = 0; ni < 4; ++ni)
            bfr[ni] = *(const bf16x8*)&Bs[(wc * 64 + ni * 16 + llo) * 32 + lhi * 8];
#pragma unroll
        for (int mi = 0; mi < 4; ++mi)
#pragma unroll
            for (int ni = 0; ni < 4; ++ni)
                acc[mi][ni] = __builtin_amdgcn_mfma_f32_16x16x32_bf16(
                    af[mi], bfr[ni], acc[mi][ni], 0, 0, 0);
    }

#pragma unroll
    for (int mi = 0; mi < 4; ++mi) {
        const int row0 = brow + wr * 64 + mi * 16 + lhi * 4;
#pragma unroll
        for (int ni = 0; ni < 4; ++ni) {
            const int col = bcol + wc * 64 + ni * 16 + llo;
            const f32x4 v = acc[mi][ni];
#pragma unroll
            for (int r = 0; r < 4; ++r) {
                const int row = row0 + r;
                if (row < M) C[(size_t)row * N + col] = f2b(v[r]);
            }
        }
    }
}

// A is fp32 (layer 1: reads x directly, converts during staging)
__global__ __launch_bounds__(256) void k_gemm_a32(const float* __restrict__ A,
                                                  const unsigned short* __restrict__ Bt,
                                                  unsigned short* __restrict__ C,
                                                  int M, int N, int K) {
    __shared__ __align__(16) short As[128 * 32];
    __shared__ __align__(16) short Bs[128 * 32];

    const int tid = threadIdx.x;
    const int w = tid >> 6;
    const int lane = tid & 63;
    const int wr = w >> 1, wc = w & 1;
    const int brow = blockIdx.x * 128;
    const int bcol = blockIdx.y * 128;
    const int lhi = lane >> 4;
    const int llo = lane & 15;

    f32x4 acc[4][4];
#pragma unroll
    for (int i = 0; i < 4; ++i)
#pragma unroll
        for (int j = 0; j < 4; ++j) acc[i][j] = (f32x4){0.f, 0.f, 0.f, 0.f};

    // A reg-staging: thread covers row tid>>1, 16 floats at (tid&1)*16
    const int arow = tid >> 1;
    const int ahalf = (tid & 1) * 16;
    int gr = brow + arow;
    gr = gr < M ? gr : M - 1;
    const float* aptr = A + (size_t)gr * K + ahalf;

    // B staging via global_load_lds
    const int srow = lane >> 2;
    const int schunk = (lane & 3) * 8;

    for (int kt = 0; kt < K; kt += 32) {
        // issue A loads early (overlap previous compute up to the barrier)
        const float4 a0 = *(const float4*)(aptr + kt);
        const float4 a1 = *(const float4*)(aptr + kt + 4);
        const float4 a2 = *(const float4*)(aptr + kt + 8);
        const float4 a3 = *(const float4*)(aptr + kt + 12);

        __syncthreads();
#pragma unroll
        for (int i = 0; i < 2; ++i) {
            const int rbase = w * 32 + i * 16;
            const int gc = bcol + rbase + srow;
            gload16(Bt + (size_t)gc * K + kt + schunk, &Bs[rbase * 32]);
        }
        ushort8 c0, c1;
        c0[0] = f2b(a0.x); c0[1] = f2b(a0.y); c0[2] = f2b(a0.z); c0[3] = f2b(a0.w);
        c0[4] = f2b(a1.x); c0[5] = f2b(a1.y); c0[6] = f2b(a1.z); c0[7] = f2b(a1.w);
        c1[0] = f2b(a2.x); c1[1] = f2b(a2.y); c1[2] = f2b(a2.z); c1[3] = f2b(a2.w);
        c1[4] = f2b(a3.x); c1[5] = f2b(a3.y); c1[6] = f2b(a3.z); c1[7] = f2b(a3.w);
        *(ushort8*)&As[arow * 32 + ahalf] = c0;
        *(ushort8*)&As[arow * 32 + ahalf + 8] = c1;
        __syncthreads();

        bf16x8 af[4], bfr[4];
#pragma unroll
        for (int mi = 0; mi < 4; ++mi)
            af[mi] = *(const bf16x8*)&As[(wr * 64 + mi * 16 + llo) * 32 + lhi * 8];
#pragma unroll
        for (int ni = 0; ni < 4; ++ni)
            bfr[ni] = *(const bf16x8*)&Bs[(wc * 64 + ni * 16 + llo) * 32 + lhi * 8];
#pragma unroll
        for (int mi = 0; mi < 4; ++mi)
#pragma unroll
            for (int ni = 0; ni < 4; ++ni)
                acc[mi][ni] = __builtin_amdgcn_mfma_f32_16x16x32_bf16(
                    af[mi], bfr[ni], acc[mi][ni], 0, 0, 0);
    }

#pragma unroll
    for (int mi = 0; mi < 4; ++mi) {
        const int row0 = brow + wr * 64 + mi * 16 + lhi * 4;
#pragma unroll
        for (int ni = 0; ni < 4; ++ni) {
            const int col = bcol + wc * 64 + ni * 16 + llo;
            const f32x4 v = acc[mi][ni];
#pragma unroll
            for (int r = 0; r < 4; ++r) {
                const int row = row0 + r;
                if (row < M) C[(size_t)row * N + col] = f2b(v[r]);
            }
        }
    }
}

// ---------------- fused aggregate: self + gather + bias + ELU ----------------
// H bf16 [N_NODES][D]; out bf16 (layer1) or fp32 (layer2). 4-deep edge unroll.

template <int D, bool BF16_OUT>
__global__ __launch_bounds__(256) void k_aggregate(const unsigned short* __restrict__ H,
                                                   const float* __restrict__ bias,
                                                   void* __restrict__ outv,
                                                   const int* __restrict__ row_start,
                                                   const int* __restrict__ csr_src,
                                                   const float* __restrict__ dinv) {
    const int wid = threadIdx.x >> 6;
    const int lane = threadIdx.x & 63;
    int n, c0;
    if (D == 512) { n = blockIdx.x * 4 + wid; c0 = lane * 8; }
    else          { n = blockIdx.x * 8 + wid * 2 + (lane >> 5); c0 = (lane & 31) * 8; }
    if (n >= N_NODES) return;

    const float di = dinv[n];
    float acc[8];
    {
        const float ws = di * di;
        ushort8 v = *(const ushort8*)(H + (size_t)n * D + c0);
#pragma unroll
        for (int e = 0; e < 8; ++e) acc[e] = b2f(v[e]) * ws;
    }

    const int e0 = row_start[n];
    const int e1 = row_start[n + 1];
    int j = e0;
    // 4 concurrent gather chains
    for (; j + 4 <= e1; j += 4) {
        const int s0 = csr_src[j + 0];
        const int s1 = csr_src[j + 1];
        const int s2 = csr_src[j + 2];
        const int s3 = csr_src[j + 3];
        const float w0 = dinv[s0] * di;
        const float w1 = dinv[s1] * di;
        const float w2 = dinv[s2] * di;
        const float w3 = dinv[s3] * di;
        const ushort8 v0 = *(const ushort8*)(H + (size_t)s0 * D + c0);
        const ushort8 v1 = *(const ushort8*)(H + (size_t)s1 * D + c0);
        const ushort8 v2 = *(const ushort8*)(H + (size_t)s2 * D + c0);
        const ushort8 v3 = *(const ushort8*)(H + (size_t)s3 * D + c0);
#pragma unroll
        for (int e = 0; e < 8; ++e) {
            acc[e] = fmaf(b2f(v0[e]), w0, acc[e]);
            acc[e] = fmaf(b2f(v1[e]), w1, acc[e]);
            acc[e] = fmaf(b2f(v2[e]), w2, acc[e]);
            acc[e] = fmaf(b2f(v3[e]), w3, acc[e]);
        }
    }
    for (; j < e1; ++j) {
        const int s = csr_src[j];
        const float ws = dinv[s] * di;
        const ushort8 v = *(const ushort8*)(H + (size_t)s * D + c0);
#pragma unroll
        for (int e = 0; e < 8; ++e) acc[e] = fmaf(b2f(v[e]), ws, acc[e]);
    }

#pragma unroll
    for (int e = 0; e < 8; ++e) {
        float t = acc[e] + bias[c0 + e];
        acc[e] = t > 0.f ? t : expf(t) - 1.f;
    }

    if (BF16_OUT) {
        ushort8 o;
#pragma unroll
        for (int e = 0; e < 8; ++e) o[e] = f2b(acc[e]);
        *(ushort8*)((unsigned short*)outv + (size_t)n * D + c0) = o;
    } else {
        float* orow = (float*)outv + (size_t)n * D + c0;
        *(float4*)orow = make_float4(acc[0], acc[1], acc[2], acc[3]);
        *(float4*)(orow + 4) = make_float4(acc[4], acc[5], acc[6], acc[7]);
    }
}

// ---------------- launch ----------------

extern "C" void kernel_launch(void* const* d_in, const int* in_sizes, int n_in,
                              void* d_out, int out_size, void* d_ws, size_t ws_size,
                              hipStream_t stream) {
    const float* x  = (const float*)d_in[0];
    const int* ei   = (const int*)d_in[1];
    const int* src  = ei;
    const int* dst  = ei + N_EDGES;
    const float* W1 = (const float*)d_in[2];
    const float* b1 = (const float*)d_in[3];
    const float* W2 = (const float*)d_in[4];
    const float* b2 = (const float*)d_in[5];
    float* out = (float*)d_out;

    char* ws = (char*)d_ws;
    size_t off = 0;
    auto alloc = [&](size_t bytes) -> void* {
        void* p = ws + off;
        off = (off + bytes + 255) & ~(size_t)255;
        return p;
    };
    int*   indeg     = (int*)alloc((size_t)N_NODES * 4);
    int*   bsum      = (int*)alloc((size_t)NB * 4);
    int*   boff      = (int*)alloc((size_t)NB * 4);
    int*   row_start = (int*)alloc((size_t)(N_NODES + 1) * 4);
    int*   cursor    = (int*)alloc((size_t)N_NODES * 4);
    int*   csr_src   = (int*)alloc((size_t)N_EDGES * 4);
    float* dinv      = (float*)alloc((size_t)N_NODES * 4);
    unsigned short* W1t  = (unsigned short*)alloc((size_t)D_H * D_IN * 2);
    unsigned short* W2t  = (unsigned short*)alloc((size_t)D_OUT * D_H * 2);
    unsigned short* H1   = (unsigned short*)alloc((size_t)N_NODES * D_H * 2);   // 51.2 MB
    unsigned short* out1 = (unsigned short*)alloc((size_t)N_NODES * D_H * 2);   // 51.2 MB
    unsigned short* H2   = (unsigned short*)alloc((size_t)N_NODES * D_OUT * 2); // 25.6 MB

    // CSR build + norms
    k_zero<<<(N_NODES + 255) / 256, 256, 0, stream>>>(indeg, N_NODES);
    k_indeg<<<(N_EDGES + 255) / 256, 256, 0, stream>>>(dst, indeg);
    k_partials<<<NB, 256, 0, stream>>>(indeg, bsum);
    k_scanb<<<1, 256, 0, stream>>>(bsum, boff);
    k_finalize<<<NB, 256, 0, stream>>>(indeg, boff, row_start, cursor, dinv);
    k_bucket<<<(N_EDGES + 255) / 256, 256, 0, stream>>>(src, dst, cursor, csr_src);

    // weight transposes
    {
        dim3 b(32, 8);
        dim3 g1(D_IN / 32, D_H / 32);
        k_wt<<<g1, b, 0, stream>>>(W1, W1t, D_IN, D_H);
        dim3 g2(D_H / 32, D_OUT / 32);
        k_wt<<<g2, b, 0, stream>>>(W2, W2t, D_H, D_OUT);
    }

    // ----- layer 1 -----
    dim3 gg1((N_NODES + 127) / 128, D_H / 128);
    k_gemm_a32<<<gg1, 256, 0, stream>>>(x, W1t, H1, N_NODES, D_H, D_IN);
    k_aggregate<512, true><<<(N_NODES + 3) / 4, 256, 0, stream>>>(H1, b1, out1, row_start, csr_src, dinv);

    // ----- layer 2 -----
    dim3 gg2((N_NODES + 127) / 128, D_OUT / 128);
    k_gemm_bf16<<<gg2, 256, 0, stream>>>(out1, W2t, H2, N_NODES, D_OUT, D_H);
    k_aggregate<256, false><<<(N_NODES + 7) / 8, 256, 0, stream>>>(H2, b2, out, row_start, csr_src, dinv);
}